// Round 4
// baseline (42.328 us; speedup 1.0000x reference)
//
#include <hip/hip_runtime.h>
#include <stdint.h>

#define NQ 900
#define TOPK_PRE 100
#define TOPK_POST 20
#define IOU_THR 0.7f
#define THREADS 256

typedef unsigned long long u64;

__device__ __forceinline__ u64 umin64(u64 a, u64 b) { return a < b ? a : b; }
__device__ __forceinline__ u64 umax64(u64 a, u64 b) { return a > b ? a : b; }

// Output layout (float32):
//   sel_s : [0,      20480)   (16,64,20)
//   sel_b : [20480, 102400)   (16,64,20,4)
//   sel_l : [102400,122880)   (16,64,20)
//   vmask : [122880,143360)   (16,64,20)

__global__ __launch_bounds__(THREADS)
void ovnms_kernel(const float* __restrict__ logits,   // (16,1,57600,2)
                  const float* __restrict__ boxes,    // (16,1,57600,4)
                  const float* __restrict__ tsize,    // (16,2) [h,w]
                  const int*   __restrict__ labels,   // (16,64)
                  float* __restrict__ out)
{
#pragma clang fp contract(off)
    const int row  = blockIdx.x;       // b*64 + p
    const int b    = row >> 6;
    const int p    = row & 63;
    const int tid  = threadIdx.x;
    const int lane = tid & 63;
    const int wid  = tid >> 6;

    __shared__ u64 wl[4 * 128];        // per-wave sorted top-128
    __shared__ u64 md[2 * 128];        // round-1 merge results
    __shared__ u64 fin[128];           // final sorted top-128
    __shared__ u64 sup0[TOPK_PRE], sup1[TOPK_PRE];
    __shared__ float x1s[TOPK_PRE], y1s[TOPK_PRE], x2s[TOPK_PRE], y2s[TOPK_PRE];
    __shared__ float areas[TOPK_PRE], scs[TOPK_PRE];
    __shared__ int   slots[TOPK_POST];
    __shared__ int   nkeep;

    // ---- 1. sigmoid scores -> 4 keys per lane (wave-local elements e = r*64+lane) ----
    const float2* l2 = (const float2*)(logits + ((size_t)b * 57600 + (size_t)p * NQ) * 2);
    u64 kr[4];
#pragma unroll
    for (int r = 0; r < 4; ++r) {
        int q = wid * 64 + lane + r * 256;      // coalesced across the block at fixed r
        u64 key = ~0ull;
        if (q < NQ) {
            float x = l2[q].y;                   // channel -1 == 1
            float s = 1.0f / (1.0f + expf(-x));
            unsigned u = __float_as_uint(s);
            key = ((u64)(~u) << 32) | (unsigned)q;
        }
        kr[r] = key;
    }

    // ---- 2. in-wave bitonic sort of 256 keys (ascending), zero barriers ----
#pragma unroll
    for (int k = 2; k <= 256; k <<= 1) {
#pragma unroll
        for (int j = k >> 1; j > 0; j >>= 1) {
            if (j >= 64) {
                const int jr = j >> 6;          // 1 or 2
#pragma unroll
                for (int r = 0; r < 4; ++r) {
                    if ((r & jr) == 0) {
                        const int rp = r | jr;
                        bool up = (((r * 64) & k) == 0);
                        u64 lo = umin64(kr[r], kr[rp]);
                        u64 hi = umax64(kr[r], kr[rp]);
                        kr[r]  = up ? lo : hi;
                        kr[rp] = up ? hi : lo;
                    }
                }
            } else {
#pragma unroll
                for (int r = 0; r < 4; ++r) {
                    bool up = (((r * 64 + lane) & k) == 0);
                    u64 part = __shfl_xor(kr[r], j);
                    bool lower = ((lane & j) == 0);
                    kr[r] = (up == lower) ? umin64(kr[r], part) : umax64(kr[r], part);
                }
            }
        }
    }

    // each wave's 128 smallest, ascending, live in kr[0] (e 0..63) and kr[1] (e 64..127)
    wl[wid * 128 + lane]      = kr[0];
    wl[wid * 128 + 64 + lane] = kr[1];
    __syncthreads();

    // ---- 3. merge round 1: waves 0,1 each merge a pair of sorted 128-lists ----
    if (wid < 2) {
        const u64* A = &wl[(2 * wid) * 128];
        const u64* B = &wl[(2 * wid + 1) * 128];
        // 128 smallest of A∪B as a bitonic sequence
        u64 c0 = umin64(A[lane],      B[127 - lane]);
        u64 c1 = umin64(A[64 + lane], B[63 - lane]);
        u64 lo = umin64(c0, c1), hi = umax64(c0, c1);   // j=64 (register-local)
        c0 = lo; c1 = hi;
#pragma unroll
        for (int j = 32; j > 0; j >>= 1) {
            bool lower = (lane & j) == 0;
            u64 p0 = __shfl_xor(c0, j);
            u64 p1 = __shfl_xor(c1, j);
            c0 = lower ? umin64(c0, p0) : umax64(c0, p0);
            c1 = lower ? umin64(c1, p1) : umax64(c1, p1);
        }
        md[wid * 128 + lane]      = c0;
        md[wid * 128 + 64 + lane] = c1;
    }
    __syncthreads();

    // ---- 4. merge round 2: wave 0 merges the two results -> exact sorted top-128 ----
    if (wid == 0) {
        const u64* A = md;
        const u64* B = md + 128;
        u64 c0 = umin64(A[lane],      B[127 - lane]);
        u64 c1 = umin64(A[64 + lane], B[63 - lane]);
        u64 lo = umin64(c0, c1), hi = umax64(c0, c1);
        c0 = lo; c1 = hi;
#pragma unroll
        for (int j = 32; j > 0; j >>= 1) {
            bool lower = (lane & j) == 0;
            u64 p0 = __shfl_xor(c0, j);
            u64 p1 = __shfl_xor(c1, j);
            c0 = lower ? umin64(c0, p0) : umax64(c0, p0);
            c1 = lower ? umin64(c1, p1) : umax64(c1, p1);
        }
        fin[lane]      = c0;
        fin[64 + lane] = c1;
    }
    __syncthreads();

    // ---- 5. gather top-100 boxes, scale, areas ----
    if (tid < TOPK_PRE) {
        u64 key = fin[tid];
        int q = (int)(key & 0xFFFFFFFFu);
        scs[tid] = __uint_as_float(~(unsigned)(key >> 32));
        const float* brow = boxes + ((size_t)b * 57600 + (size_t)p * NQ + (size_t)q) * 4;
        float cx = brow[0], cy = brow[1], w = brow[2], h = brow[3];
        float ih = tsize[b * 2 + 0];
        float iw = tsize[b * 2 + 1];
        float xa = (cx - 0.5f * w) * iw;
        float ya = (cy - 0.5f * h) * ih;
        float xb = (cx + 0.5f * w) * iw;
        float yb = (cy + 0.5f * h) * ih;
        x1s[tid] = xa; y1s[tid] = ya; x2s[tid] = xb; y2s[tid] = yb;
        areas[tid] = fmaxf(xb - xa, 0.0f) * fmaxf(yb - ya, 0.0f);
    }
    __syncthreads();

    // ---- 6. suppression bit-matrix via ballot (no barriers inside) ----
    for (int i = wid; i < TOPK_PRE; i += 4) {
        float xi1 = x1s[i], yi1 = y1s[i], xi2 = x2s[i], yi2 = y2s[i], ai = areas[i];
        int j = lane;
        bool b0 = false;
        if (j < i) {
            float ltx = fmaxf(xi1, x1s[j]);
            float lty = fmaxf(yi1, y1s[j]);
            float rbx = fminf(xi2, x2s[j]);
            float rby = fminf(yi2, y2s[j]);
            float wx = fmaxf(rbx - ltx, 0.0f);
            float wy = fmaxf(rby - lty, 0.0f);
            float inter = wx * wy;
            float iou = inter / (((ai + areas[j]) - inter) + 1e-7f);
            b0 = iou > IOU_THR;
        }
        u64 m0 = __ballot(b0);
        j = 64 + lane;
        bool b1 = false;
        if (j < i) {
            float ltx = fmaxf(xi1, x1s[j]);
            float lty = fmaxf(yi1, y1s[j]);
            float rbx = fminf(xi2, x2s[j]);
            float rby = fminf(yi2, y2s[j]);
            float wx = fmaxf(rbx - ltx, 0.0f);
            float wy = fmaxf(rby - lty, 0.0f);
            float inter = wx * wy;
            float iou = inter / (((ai + areas[j]) - inter) + 1e-7f);
            b1 = iou > IOU_THR;
        }
        u64 m1 = __ballot(b1);
        if (lane == 0) { sup0[i] = m0; sup1[i] = m1; }
    }
    __syncthreads();

    // ---- 7. greedy scan over bitmasks (single thread, pure ALU) ----
    if (tid == 0) {
        u64 kept0 = 0, kept1 = 0;
        int r = 0;
#pragma unroll 10
        for (int i = 0; i < TOPK_PRE; ++i) {
            u64 s0 = sup0[i] & kept0;
            u64 s1 = sup1[i] & kept1;
            if ((s0 | s1) == 0ull) {
                if (i < 64) kept0 |= 1ull << i;
                else        kept1 |= 1ull << (i - 64);
                if (r < TOPK_POST) slots[r] = i;
                r++;
            }
        }
        nkeep = r < TOPK_POST ? r : TOPK_POST;
    }
    __syncthreads();

    // ---- 8. write outputs ----
    if (tid < TOPK_POST) {
        size_t o = (size_t)row * TOPK_POST + (size_t)tid;
        float s = 0.0f, xa = 0.0f, ya = 0.0f, xb = 0.0f, yb = 0.0f;
        float lab = -1.0f, m = 0.0f;
        if (tid < nkeep) {
            int i = slots[tid];
            s = scs[i];
            xa = x1s[i]; ya = y1s[i]; xb = x2s[i]; yb = y2s[i];
            lab = (float)labels[row];
            m = 1.0f;
        }
        out[o] = s;
        float* ob = out + 20480 + o * 4;
        ob[0] = xa; ob[1] = ya; ob[2] = xb; ob[3] = yb;
        out[102400 + o] = lab;
        out[122880 + o] = m;
    }
}

extern "C" void kernel_launch(void* const* d_in, const int* in_sizes, int n_in,
                              void* d_out, int out_size, void* d_ws, size_t ws_size,
                              hipStream_t stream) {
    const float* logits = (const float*)d_in[0];
    const float* boxes  = (const float*)d_in[1];
    const float* tsize  = (const float*)d_in[2];
    const int*   labels = (const int*)d_in[3];
    float* out = (float*)d_out;

    ovnms_kernel<<<dim3(1024), dim3(THREADS), 0, stream>>>(logits, boxes, tsize, labels, out);
}

// Round 5
// 37.066 us; speedup vs baseline: 1.1420x; 1.1420x over previous
//
#include <hip/hip_runtime.h>
#include <stdint.h>

#define NQ 900
#define TOPK_PRE 100
#define TOPK_POST 20
#define IOU_THR 0.7f
#define THREADS 256

typedef unsigned long long u64;

__device__ __forceinline__ u64 umin64(u64 a, u64 b) { return a < b ? a : b; }
__device__ __forceinline__ u64 umax64(u64 a, u64 b) { return a > b ? a : b; }

// Output layout (float32):
//   sel_s : [0,      20480)   (16,64,20)
//   sel_b : [20480, 102400)   (16,64,20,4)
//   sel_l : [102400,122880)   (16,64,20)
//   vmask : [122880,143360)   (16,64,20)

__global__ __launch_bounds__(THREADS)
void ovnms_kernel(const float* __restrict__ logits,   // (16,1,57600,2)
                  const float* __restrict__ boxes,    // (16,1,57600,4)
                  const float* __restrict__ tsize,    // (16,2) [h,w]
                  const int*   __restrict__ labels,   // (16,64)
                  float* __restrict__ out)
{
#pragma clang fp contract(off)
    const int row  = blockIdx.x;       // b*64 + p
    const int b    = row >> 6;
    const int p    = row & 63;
    const int tid  = threadIdx.x;
    const int lane = tid & 63;
    const int wid  = tid >> 6;

    __shared__ u64 wl[4 * 128];        // per-wave sorted top-128
    __shared__ u64 md[2 * 128];        // round-1 merge results
    __shared__ u64 fin[128];           // final sorted top-128
    __shared__ u64 sup0[TOPK_PRE], sup1[TOPK_PRE];
    __shared__ float x1s[TOPK_PRE], y1s[TOPK_PRE], x2s[TOPK_PRE], y2s[TOPK_PRE];
    __shared__ float areas[TOPK_PRE], scs[TOPK_PRE];
    __shared__ u64 keep0s, keep1s;

    // ---- 1. sigmoid scores -> 4 keys per lane (wave-local elements e = r*64+lane) ----
    const float2* l2 = (const float2*)(logits + ((size_t)b * 57600 + (size_t)p * NQ) * 2);
    u64 kr[4];
#pragma unroll
    for (int r = 0; r < 4; ++r) {
        int q = wid * 64 + lane + r * 256;
        u64 key = ~0ull;
        if (q < NQ) {
            float x = l2[q].y;                   // channel -1 == 1
            float s = 1.0f / (1.0f + expf(-x));
            unsigned u = __float_as_uint(s);
            key = ((u64)(~u) << 32) | (unsigned)q;
        }
        kr[r] = key;
    }

    // ---- 2. in-wave bitonic sort of 256 keys (ascending), zero barriers ----
#pragma unroll
    for (int k = 2; k <= 256; k <<= 1) {
#pragma unroll
        for (int j = k >> 1; j > 0; j >>= 1) {
            if (j >= 64) {
                const int jr = j >> 6;          // 1 or 2
#pragma unroll
                for (int r = 0; r < 4; ++r) {
                    if ((r & jr) == 0) {
                        const int rp = r | jr;
                        bool up = (((r * 64) & k) == 0);
                        u64 lo = umin64(kr[r], kr[rp]);
                        u64 hi = umax64(kr[r], kr[rp]);
                        kr[r]  = up ? lo : hi;
                        kr[rp] = up ? hi : lo;
                    }
                }
            } else {
#pragma unroll
                for (int r = 0; r < 4; ++r) {
                    bool up = (((r * 64 + lane) & k) == 0);
                    u64 part = __shfl_xor(kr[r], j);
                    bool lower = ((lane & j) == 0);
                    kr[r] = (up == lower) ? umin64(kr[r], part) : umax64(kr[r], part);
                }
            }
        }
    }

    wl[wid * 128 + lane]      = kr[0];
    wl[wid * 128 + 64 + lane] = kr[1];
    __syncthreads();

    // ---- 3. merge round 1: waves 0,1 each merge a pair of sorted 128-lists ----
    if (wid < 2) {
        const u64* A = &wl[(2 * wid) * 128];
        const u64* B = &wl[(2 * wid + 1) * 128];
        u64 c0 = umin64(A[lane],      B[127 - lane]);
        u64 c1 = umin64(A[64 + lane], B[63 - lane]);
        u64 lo = umin64(c0, c1), hi = umax64(c0, c1);
        c0 = lo; c1 = hi;
#pragma unroll
        for (int j = 32; j > 0; j >>= 1) {
            bool lower = (lane & j) == 0;
            u64 p0 = __shfl_xor(c0, j);
            u64 p1 = __shfl_xor(c1, j);
            c0 = lower ? umin64(c0, p0) : umax64(c0, p0);
            c1 = lower ? umin64(c1, p1) : umax64(c1, p1);
        }
        md[wid * 128 + lane]      = c0;
        md[wid * 128 + 64 + lane] = c1;
    }
    __syncthreads();

    // ---- 4. merge round 2: wave 0 merges the two results -> exact sorted top-128 ----
    if (wid == 0) {
        const u64* A = md;
        const u64* B = md + 128;
        u64 c0 = umin64(A[lane],      B[127 - lane]);
        u64 c1 = umin64(A[64 + lane], B[63 - lane]);
        u64 lo = umin64(c0, c1), hi = umax64(c0, c1);
        c0 = lo; c1 = hi;
#pragma unroll
        for (int j = 32; j > 0; j >>= 1) {
            bool lower = (lane & j) == 0;
            u64 p0 = __shfl_xor(c0, j);
            u64 p1 = __shfl_xor(c1, j);
            c0 = lower ? umin64(c0, p0) : umax64(c0, p0);
            c1 = lower ? umin64(c1, p1) : umax64(c1, p1);
        }
        fin[lane]      = c0;
        fin[64 + lane] = c1;
    }
    __syncthreads();

    // ---- 5. gather top-100 boxes, scale, areas ----
    if (tid < TOPK_PRE) {
        u64 key = fin[tid];
        int q = (int)(key & 0xFFFFFFFFu);
        scs[tid] = __uint_as_float(~(unsigned)(key >> 32));
        const float* brow = boxes + ((size_t)b * 57600 + (size_t)p * NQ + (size_t)q) * 4;
        float cx = brow[0], cy = brow[1], w = brow[2], h = brow[3];
        float ih = tsize[b * 2 + 0];
        float iw = tsize[b * 2 + 1];
        float xa = (cx - 0.5f * w) * iw;
        float ya = (cy - 0.5f * h) * ih;
        float xb = (cx + 0.5f * w) * iw;
        float yb = (cy + 0.5f * h) * ih;
        x1s[tid] = xa; y1s[tid] = ya; x2s[tid] = xb; y2s[tid] = yb;
        areas[tid] = fmaxf(xb - xa, 0.0f) * fmaxf(yb - ya, 0.0f);
    }
    __syncthreads();

    // ---- 6. suppression bit-matrix via ballot; lane-j boxes cached in registers ----
    {
        const float xj1a = x1s[lane], yj1a = y1s[lane];
        const float xj2a = x2s[lane], yj2a = y2s[lane], aja = areas[lane];
        const int  j2   = lane + 64;
        const bool hv2  = j2 < TOPK_PRE;
        const int  j2c  = hv2 ? j2 : 0;
        const float xj1b = x1s[j2c], yj1b = y1s[j2c];
        const float xj2b = x2s[j2c], yj2b = y2s[j2c], ajb = areas[j2c];

#pragma unroll 5
        for (int i = wid; i < TOPK_PRE; i += 4) {
            float xi1 = x1s[i], yi1 = y1s[i], xi2 = x2s[i], yi2 = y2s[i], ai = areas[i];
            bool b0 = false;
            if (lane < i) {
                float ltx = fmaxf(xi1, xj1a);
                float lty = fmaxf(yi1, yj1a);
                float rbx = fminf(xi2, xj2a);
                float rby = fminf(yi2, yj2a);
                float wx = fmaxf(rbx - ltx, 0.0f);
                float wy = fmaxf(rby - lty, 0.0f);
                float inter = wx * wy;
                float iou = inter / (((ai + aja) - inter) + 1e-7f);
                b0 = iou > IOU_THR;
            }
            u64 m0 = __ballot(b0);
            bool b1 = false;
            if (hv2 && j2 < i) {
                float ltx = fmaxf(xi1, xj1b);
                float lty = fmaxf(yi1, yj1b);
                float rbx = fminf(xi2, xj2b);
                float rby = fminf(yi2, yj2b);
                float wx = fmaxf(rbx - ltx, 0.0f);
                float wy = fmaxf(rby - lty, 0.0f);
                float inter = wx * wy;
                float iou = inter / (((ai + ajb) - inter) + 1e-7f);
                b1 = iou > IOU_THR;
            }
            u64 m1 = __ballot(b1);
            if (lane == 0) { sup0[i] = m0; sup1[i] = m1; }
        }
    }
    __syncthreads();

    // ---- 7. greedy scan, transposed: registers + ballot only (wave 0) ----
    if (wid == 0) {
        u64 r0a = sup0[lane];              // suppressors i<64 of row lane
        u64 r1a = sup1[lane];              // suppressors i in [64,100)
        const int  j2  = lane + 64;
        const bool hv2 = j2 < TOPK_PRE;
        u64 r0b = hv2 ? sup0[j2] : 0ull;
        u64 r1b = hv2 ? sup1[j2] : 0ull;
        bool alive_a = true;
        bool alive_b = hv2;

#pragma unroll 4
        for (int i = 0; i < 64; ++i) {
            u64 bal = __ballot(alive_a);
            if ((bal >> i) & 1ull) {       // candidate i alive (wave-uniform)
                alive_a = alive_a && !((r0a >> i) & 1ull);
                alive_b = alive_b && !((r0b >> i) & 1ull);
            }
        }
#pragma unroll 4
        for (int i = 64; i < TOPK_PRE; ++i) {
            u64 bal = __ballot(alive_b);
            if ((bal >> (i - 64)) & 1ull) {
                alive_a = alive_a && !((r1a >> (i - 64)) & 1ull);
                alive_b = alive_b && !((r1b >> (i - 64)) & 1ull);
            }
        }
        u64 B0 = __ballot(alive_a);
        u64 B1 = __ballot(alive_b);
        if (lane == 0) { keep0s = B0; keep1s = B1; }
    }
    __syncthreads();

    // ---- 8. write outputs: thread t takes the t-th kept row ----
    if (tid < TOPK_POST) {
        u64 K0 = keep0s, K1 = keep1s;
        int c0 = __popcll(K0);
        int idx = -1;
        if (tid < c0) {
            u64 x = K0;
            for (int k = 0; k < tid; ++k) x &= x - 1;
            idx = __ffsll(x) - 1;
        } else {
            int t = tid - c0;
            if (t < __popcll(K1)) {
                u64 x = K1;
                for (int k = 0; k < t; ++k) x &= x - 1;
                idx = 64 + __ffsll(x) - 1;
            }
        }
        size_t o = (size_t)row * TOPK_POST + (size_t)tid;
        float s = 0.0f, xa = 0.0f, ya = 0.0f, xb = 0.0f, yb = 0.0f;
        float lab = -1.0f, m = 0.0f;
        if (idx >= 0) {
            s = scs[idx];
            xa = x1s[idx]; ya = y1s[idx]; xb = x2s[idx]; yb = y2s[idx];
            lab = (float)labels[row];
            m = 1.0f;
        }
        out[o] = s;
        float* ob = out + 20480 + o * 4;
        ob[0] = xa; ob[1] = ya; ob[2] = xb; ob[3] = yb;
        out[102400 + o] = lab;
        out[122880 + o] = m;
    }
}

extern "C" void kernel_launch(void* const* d_in, const int* in_sizes, int n_in,
                              void* d_out, int out_size, void* d_ws, size_t ws_size,
                              hipStream_t stream) {
    const float* logits = (const float*)d_in[0];
    const float* boxes  = (const float*)d_in[1];
    const float* tsize  = (const float*)d_in[2];
    const int*   labels = (const int*)d_in[3];
    float* out = (float*)d_out;

    ovnms_kernel<<<dim3(1024), dim3(THREADS), 0, stream>>>(logits, boxes, tsize, labels, out);
}